// Round 8
// baseline (170.553 us; speedup 1.0000x reference)
//
#include <hip/hip_runtime.h>
#include <hip/hip_bf16.h>

typedef __attribute__((ext_vector_type(8))) short bf16x8;
typedef __attribute__((ext_vector_type(8))) unsigned short u16x8;
typedef __attribute__((ext_vector_type(4))) float f32x4;
typedef __attribute__((ext_vector_type(16))) float f32x16;

#define SEQ   8192
#define DEM   256
#define CHUNK 512
#define NTASKS 272      // sum over 32 qtiles (256 rows) of (q>>1)+1

#define GLOAD_LDS16(g, l) \
  __builtin_amdgcn_global_load_lds((const __attribute__((address_space(1))) void*)(g), \
                                   (__attribute__((address_space(3))) void*)(l), 16, 0, 0)

static __device__ __forceinline__ unsigned short f2bf(float f) {
  union { float f; unsigned int u; } v; v.f = f;
  return (unsigned short)((v.u + 0x7fffu + ((v.u >> 16) & 1u)) >> 16);
}
static __device__ __forceinline__ float bf2f(unsigned short h) {
  union { unsigned int u; float f; } v; v.u = ((unsigned int)h) << 16;
  return v.f;
}

// ---- projections: qb[s][d] = (log2e/16)*sum_e x[s][e] Wq[d][e] (scale+log2e folded);
//      kb[s][d] = sum_e x[s][e] Wk[d][e]; vtb[d][s] = sum_e x[s][e] Wv[d][e]
__global__ __launch_bounds__(256) void proj_kernel(
    const float* __restrict__ x,  const float* __restrict__ Wq,
    const float* __restrict__ Wk, const float* __restrict__ Wv,
    unsigned short* __restrict__ qb, unsigned short* __restrict__ kb,
    unsigned short* __restrict__ vtb)
{
  const int m0 = blockIdx.x * 128;
  const int n0 = blockIdx.y * 128;
  const int which = blockIdx.z;
  const float* __restrict__ W = (which == 0) ? Wq : (which == 1) ? Wk : Wv;

  __shared__ unsigned short As[128 * 64];
  __shared__ unsigned short Bs[128 * 64];

  const int tid  = threadIdx.x;
  const int wave = tid >> 6, lane = tid & 63;
  const int wm = wave >> 1, wn = wave & 1;
  const int lr = lane & 15, lg = lane >> 4;

  f32x4 acc[4][4];
  #pragma unroll
  for (int i = 0; i < 4; i++)
    #pragma unroll
    for (int j = 0; j < 4; j++) acc[i][j] = (f32x4){0.f, 0.f, 0.f, 0.f};

  for (int k0 = 0; k0 < DEM; k0 += 64) {
    __syncthreads();
    #pragma unroll
    for (int p = 0; p < 8; p++) {
      int c   = p * 256 + tid;
      int row = c >> 4;
      int col = (c & 15) << 2;
      float4 fA = *reinterpret_cast<const float4*>(&x[(m0 + row) * DEM + k0 + col]);
      float4 fB = *reinterpret_cast<const float4*>(&W[(n0 + row) * DEM + k0 + col]);
      uint2 hA, hB;
      hA.x = f2bf(fA.x) | ((unsigned)f2bf(fA.y) << 16);
      hA.y = f2bf(fA.z) | ((unsigned)f2bf(fA.w) << 16);
      hB.x = f2bf(fB.x) | ((unsigned)f2bf(fB.y) << 16);
      hB.y = f2bf(fB.z) | ((unsigned)f2bf(fB.w) << 16);
      int byte = (row * 128 + (col << 1)) ^ ((row & 7) << 4);
      *reinterpret_cast<uint2*>(reinterpret_cast<char*>(As) + byte) = hA;
      *reinterpret_cast<uint2*>(reinterpret_cast<char*>(Bs) + byte) = hB;
    }
    __syncthreads();

    #pragma unroll
    for (int ks = 0; ks < 2; ks++) {
      bf16x8 a[4], b[4];
      #pragma unroll
      for (int mt = 0; mt < 4; mt++) {
        int row  = wm * 64 + mt * 16 + lr;
        int byte = (row * 128 + ks * 64 + lg * 16) ^ ((row & 7) << 4);
        a[mt] = *reinterpret_cast<const bf16x8*>(reinterpret_cast<const char*>(As) + byte);
      }
      #pragma unroll
      for (int nt = 0; nt < 4; nt++) {
        int row  = wn * 64 + nt * 16 + lr;
        int byte = (row * 128 + ks * 64 + lg * 16) ^ ((row & 7) << 4);
        b[nt] = *reinterpret_cast<const bf16x8*>(reinterpret_cast<const char*>(Bs) + byte);
      }
      #pragma unroll
      for (int mt = 0; mt < 4; mt++)
        #pragma unroll
        for (int nt = 0; nt < 4; nt++)
          acc[mt][nt] = __builtin_amdgcn_mfma_f32_16x16x32_bf16(a[mt], b[nt], acc[mt][nt], 0, 0, 0);
    }
  }

  // fold 1/sqrt(256) * log2(e) into Q (softmax done in exp2 domain)
  const float osc = (which == 0) ? 0.0625f * 1.4426950408889634f : 1.0f;
  #pragma unroll
  for (int mt = 0; mt < 4; mt++)
    #pragma unroll
    for (int nt = 0; nt < 4; nt++)
      #pragma unroll
      for (int r = 0; r < 4; r++) {
        int row = m0 + wm * 64 + mt * 16 + lg * 4 + r;
        int col = n0 + wn * 64 + nt * 16 + lr;
        unsigned short h = f2bf(acc[mt][nt][r] * osc);
        if (which == 0)      qb[row * DEM + col]  = h;
        else if (which == 1) kb[row * DEM + col]  = h;
        else                 vtb[(size_t)col * SEQ + row] = h;
      }
}

// ---- attention: task = (qtile of 256 rows, kv chunk <=512). 8 waves x 32 q-rows.
// 32x32x16 MFMA. Swapped ops: QK = K*Q^T (lane owns q=lane&31); PV computes
// O^T = V^T * P^T so accumulator col = q too (no rescale shuffles). K,V double-
// buffered LDS via global_load_lds w16; P 2KB/wave sub-buffer. Defer-max (T13).
__global__ __launch_bounds__(512, 2) void attn_kernel(
    const unsigned short* __restrict__ qb, const unsigned short* __restrict__ kb,
    const unsigned short* __restrict__ vtb,
    unsigned short* __restrict__ pOb, float* __restrict__ ml)
{
  __shared__ char lds[147456];
  char* Ks = lds;               // 2 x 32KB K tiles [64 kv x 512B], swizzled
  char* Vs = lds + 65536;       // 2 x 32KB Vt tiles [256 d x 128B], swizzled
  char* Ps = lds + 131072;      // 8 waves x 2KB P-sub [32 q x 64B], swizzled

  // ---- task decode: nch(q) = (q>>1)+1, prefix = (a+b)*(a+1), a=q>>1, b=q&1
  const int t = NTASKS - 1 - (int)blockIdx.x;   // largest q first
  int q = 0, s = 0;
  for (;;) { int n = (q >> 1) + 1; if (t < s + n) break; s += n; ++q; }
  const int c = t - s;
  const int kv_lo = c * CHUNK;
  const int kv_hi_blk = min(kv_lo + CHUNK, (q + 1) * 256);

  const int tid = threadIdx.x;
  const int wave = tid >> 6, lane = tid & 63;
  const int ql = lane & 31;          // this lane's q (col index everywhere)
  const int hi = lane >> 5;
  const int qrow = q * 256 + wave * 32;
  const int kv_hi_w = min(kv_hi_blk, ((qrow + 32 + 63) >> 6) << 6);
  char* pb = Ps + wave * 2048;

  // ---- Q fragments hoisted (B-operand: col=ql, k = i*16 + hi*8 + j)
  bf16x8 qf[16];
  {
    const unsigned short* qp = qb + (size_t)(qrow + ql) * DEM + hi * 8;
    #pragma unroll
    for (int i = 0; i < 16; i++) qf[i] = *reinterpret_cast<const bf16x8*>(qp + i * 16);
  }

  f32x16 o[8];   // O^T: o[dt][rg] -> q=ql, d = dt*32 + (rg&3)+8*(rg>>2)+4*hi
  #pragma unroll
  for (int dt = 0; dt < 8; dt++)
    #pragma unroll
    for (int rg = 0; rg < 16; rg++) o[dt][rg] = 0.f;
  float m_run = -3.0e38f, l_run = 0.f;   // per-lane, q = qrow + ql (log2 domain)

  // ---- prologue: stage K(0), V(0) into buf 0
  #pragma unroll
  for (int i = 0; i < 4; i++) {
    int sl = i * 8192 + tid * 16;
    int krow = sl >> 9;
    int kin  = (sl & 511) ^ ((krow & 7) << 4);
    GLOAD_LDS16((const char*)kb + (((size_t)(kv_lo + krow)) << 9) + kin,
                Ks + i * 8192 + (wave << 10));
    int vrow = sl >> 7;
    int vin  = (sl & 127) ^ ((vrow & 7) << 4);
    GLOAD_LDS16((const char*)vtb + ((size_t)vrow * SEQ + kv_lo) * 2 + vin,
                Vs + i * 8192 + (wave << 10));
  }
  __syncthreads();

  const int nsteps = (kv_hi_blk - kv_lo) >> 6;
  for (int st = 0; st < nsteps; st++) {
    const int kv0 = kv_lo + (st << 6);
    const int buf = st & 1;
    // ---- async stage K(t+1), V(t+1) into buf^1
    if (st + 1 < nsteps) {
      #pragma unroll
      for (int i = 0; i < 4; i++) {
        int sl = i * 8192 + tid * 16;
        int krow = sl >> 9;
        int kin  = (sl & 511) ^ ((krow & 7) << 4);
        GLOAD_LDS16((const char*)kb + (((size_t)(kv0 + 64 + krow)) << 9) + kin,
                    Ks + (buf ^ 1) * 32768 + i * 8192 + (wave << 10));
        int vrow = sl >> 7;
        int vin  = (sl & 127) ^ ((vrow & 7) << 4);
        GLOAD_LDS16((const char*)vtb + ((size_t)vrow * SEQ + kv0 + 64) * 2 + vin,
                    Vs + (buf ^ 1) * 32768 + i * 8192 + (wave << 10));
      }
    }

    const bool act = kv0 < kv_hi_w;
    if (act) {
      // ---- QK^T swapped: sc[sub] = K_sub x Q^T (A=K row=ql+sub*32, B=Q col=ql)
      f32x16 sc0, sc1;
      #pragma unroll
      for (int rg = 0; rg < 16; rg++) { sc0[rg] = 0.f; sc1[rg] = 0.f; }
      const char* kbase = Ks + buf * 32768;
      const int r0 = ql, r1 = 32 + ql;
      const int rsw = (ql & 7) << 4;
      __builtin_amdgcn_s_setprio(1);
      #pragma unroll
      for (int i = 0; i < 16; i++) {
        int off = (i * 32 + hi * 16) ^ rsw;
        bf16x8 kf0 = *reinterpret_cast<const bf16x8*>(kbase + r0 * 512 + off);
        bf16x8 kf1 = *reinterpret_cast<const bf16x8*>(kbase + r1 * 512 + off);
        sc0 = __builtin_amdgcn_mfma_f32_32x32x16_bf16(kf0, qf[i], sc0, 0, 0, 0);
        sc1 = __builtin_amdgcn_mfma_f32_32x32x16_bf16(kf1, qf[i], sc1, 0, 0, 0);
      }
      __builtin_amdgcn_s_setprio(0);

      // ---- mask + per-lane online softmax (log2 domain), q = qrow + ql
      const int qg = qrow + ql;
      if (kv0 + 63 > qrow) {
        #pragma unroll
        for (int rg = 0; rg < 16; rg++) {
          int kvp = kv0 + (rg & 3) + 8 * (rg >> 2) + 4 * hi;
          if (kvp      > qg) sc0[rg] = -3.0e38f;
          if (kvp + 32 > qg) sc1[rg] = -3.0e38f;
        }
      }
      float pmax = fmaxf(sc0[0], sc1[0]);
      #pragma unroll
      for (int rg = 1; rg < 16; rg++) pmax = fmaxf(pmax, fmaxf(sc0[rg], sc1[rg]));
      pmax = fmaxf(pmax, __shfl_xor(pmax, 32));

      float mnew;
      if (__all(pmax <= m_run + 11.0f)) {          // defer-max (T13)
        mnew = m_run;
      } else {
        mnew = fmaxf(m_run, pmax);
        const float cr = __builtin_amdgcn_exp2f(m_run - mnew);
        #pragma unroll
        for (int dt = 0; dt < 8; dt++)
          #pragma unroll
          for (int rg = 0; rg < 16; rg++) o[dt][rg] *= cr;
        l_run *= cr;
        m_run = mnew;
      }

      float sum = 0.f;
      uint2 w0[4], w1[4];    // packed P, sub0/sub1, 4 consecutive kv each
      #pragma unroll
      for (int tq = 0; tq < 4; tq++) {
        float e00 = __builtin_amdgcn_exp2f(sc0[tq*4+0] - mnew);
        float e01 = __builtin_amdgcn_exp2f(sc0[tq*4+1] - mnew);
        float e02 = __builtin_amdgcn_exp2f(sc0[tq*4+2] - mnew);
        float e03 = __builtin_amdgcn_exp2f(sc0[tq*4+3] - mnew);
        float e10 = __builtin_amdgcn_exp2f(sc1[tq*4+0] - mnew);
        float e11 = __builtin_amdgcn_exp2f(sc1[tq*4+1] - mnew);
        float e12 = __builtin_amdgcn_exp2f(sc1[tq*4+2] - mnew);
        float e13 = __builtin_amdgcn_exp2f(sc1[tq*4+3] - mnew);
        sum += (e00 + e01) + (e02 + e03) + (e10 + e11) + (e12 + e13);
        w0[tq].x = (unsigned)f2bf(e00) | ((unsigned)f2bf(e01) << 16);
        w0[tq].y = (unsigned)f2bf(e02) | ((unsigned)f2bf(e03) << 16);
        w1[tq].x = (unsigned)f2bf(e10) | ((unsigned)f2bf(e11) << 16);
        w1[tq].y = (unsigned)f2bf(e12) | ((unsigned)f2bf(e13) << 16);
      }
      sum += __shfl_xor(sum, 32);
      l_run += sum;

      // ---- per-sub: P -> LDS (4 b64), pf read (2 b128), 16 PV MFMA
      const char* vbase = Vs + buf * 32768;
      const int psw = (ql & 3) << 4;
      #pragma unroll
      for (int sub = 0; sub < 2; sub++) {
        #pragma unroll
        for (int tq = 0; tq < 4; tq++)
          *reinterpret_cast<uint2*>(pb + ql * 64 + ((tq * 16 + hi * 8) ^ psw)) =
              sub ? w1[tq] : w0[tq];
        bf16x8 pf0 = *reinterpret_cast<const bf16x8*>(pb + ql * 64 + ((hi * 16) ^ psw));
        bf16x8 pf1 = *reinterpret_cast<const bf16x8*>(pb + ql * 64 + ((32 + hi * 16) ^ psw));
        __builtin_amdgcn_s_setprio(1);
        #pragma unroll
        for (int dt = 0; dt < 8; dt++) {
          const int vrow = dt * 32 + ql;
          const char* vp = vbase + vrow * 128;
          const int vsw = (vrow & 7) << 4;
          bf16x8 vf0 = *reinterpret_cast<const bf16x8*>(vp + ((sub * 64 + hi * 16) ^ vsw));
          bf16x8 vf1 = *reinterpret_cast<const bf16x8*>(vp + ((sub * 64 + 32 + hi * 16) ^ vsw));
          o[dt] = __builtin_amdgcn_mfma_f32_32x32x16_bf16(vf0, pf0, o[dt], 0, 0, 0);
          o[dt] = __builtin_amdgcn_mfma_f32_32x32x16_bf16(vf1, pf1, o[dt], 0, 0, 0);
        }
        __builtin_amdgcn_s_setprio(0);
      }
    }
    __syncthreads();   // drains stage(t+1); buffers safe to flip
  }

  // ---- write partials: O^T lane mapping q=ql, d = dt*32 + (rg&3)+8*(rg>>2)+4*hi
  const size_t obase = (size_t)t * (256 * 256);
  const int row_l = wave * 32 + ql;
  #pragma unroll
  for (int dt = 0; dt < 8; dt++)
    #pragma unroll
    for (int tq = 0; tq < 4; tq++) {
      const int d = dt * 32 + tq * 8 + hi * 4;
      uint2 w;
      w.x = (unsigned)f2bf(o[dt][tq*4+0]) | ((unsigned)f2bf(o[dt][tq*4+1]) << 16);
      w.y = (unsigned)f2bf(o[dt][tq*4+2]) | ((unsigned)f2bf(o[dt][tq*4+3]) << 16);
      *reinterpret_cast<uint2*>(&pOb[obase + (size_t)row_l * 256 + d]) = w;
    }
  if (hi == 0) {
    ml[(size_t)t * 512 + row_l * 2]     = m_run;
    ml[(size_t)t * 512 + row_l * 2 + 1] = l_run;
  }
}

// ---- merge partials (log2-domain m)
__global__ __launch_bounds__(256) void merge_kernel(
    const unsigned short* __restrict__ pOb, const float* __restrict__ ml,
    float* __restrict__ out)
{
  const int tid = threadIdx.x;
  const int row = blockIdx.x * 32 + (tid >> 3);
  const int c0  = (tid & 7) * 32;
  const int q = row >> 8;              // 256-row qtile, 0..31
  const int a = q >> 1, b = q & 1;
  const int n = a + 1;                 // chunks for this qtile
  const int base = (a + b) * (a + 1);
  const int lrow = row & 255;

  float M = -3.0e38f;
  for (int i = 0; i < n; i++)
    M = fmaxf(M, ml[(size_t)(base + i) * 512 + lrow * 2]);

  float L = 0.f;
  float acc[32];
  #pragma unroll
  for (int j = 0; j < 32; j++) acc[j] = 0.f;

  for (int i = 0; i < n; i++) {
    const float mi = ml[(size_t)(base + i) * 512 + lrow * 2];
    const float li = ml[(size_t)(base + i) * 512 + lrow * 2 + 1];
    const float fi = __builtin_amdgcn_exp2f(mi - M);
    L += li * fi;
    const unsigned short* src = pOb + (size_t)(base + i) * (256 * 256) + (size_t)lrow * 256 + c0;
    #pragma unroll
    for (int v = 0; v < 4; v++) {
      u16x8 u = *reinterpret_cast<const u16x8*>(src + v * 8);
      #pragma unroll
      for (int j = 0; j < 8; j++) acc[v * 8 + j] += bf2f((unsigned short)u[j]) * fi;
    }
  }
  const float inv = 1.f / L;
  #pragma unroll
  for (int v = 0; v < 8; v++) {
    float4 w;
    w.x = acc[v * 4 + 0] * inv; w.y = acc[v * 4 + 1] * inv;
    w.z = acc[v * 4 + 2] * inv; w.w = acc[v * 4 + 3] * inv;
    *reinterpret_cast<float4*>(&out[(size_t)row * 256 + c0 + v * 4]) = w;
  }
}

extern "C" void kernel_launch(void* const* d_in, const int* in_sizes, int n_in,
                              void* d_out, int out_size, void* d_ws, size_t ws_size,
                              hipStream_t stream)
{
  const float* x  = (const float*)d_in[0];
  const float* Wq = (const float*)d_in[1];
  const float* Wk = (const float*)d_in[2];
  const float* Wv = (const float*)d_in[3];

  char* ws = (char*)d_ws;
  unsigned short* qb  = (unsigned short*)ws;                              // 4 MB
  unsigned short* kb  = (unsigned short*)(ws + (size_t)4  * 1024 * 1024); // 4 MB
  unsigned short* vtb = (unsigned short*)(ws + (size_t)8  * 1024 * 1024); // 4 MB
  float*          ml  = (float*)         (ws + (size_t)12 * 1024 * 1024); // 544 KB
  unsigned short* pOb = (unsigned short*)(ws + (size_t)13 * 1024 * 1024); // 35.7 MB

  proj_kernel<<<dim3(64, 2, 3), 256, 0, stream>>>(x, Wq, Wk, Wv, qb, kb, vtb);
  attn_kernel<<<dim3(NTASKS), 512, 0, stream>>>(qb, kb, vtb, pOb, ml);
  merge_kernel<<<dim3(SEQ / 32), 256, 0, stream>>>(pOb, ml, (float*)d_out);
}

// Round 9
// 169.207 us; speedup vs baseline: 1.0080x; 1.0080x over previous
//
#include <hip/hip_runtime.h>
#include <hip/hip_bf16.h>

typedef __attribute__((ext_vector_type(8))) short bf16x8;
typedef __attribute__((ext_vector_type(8))) unsigned short u16x8;
typedef __attribute__((ext_vector_type(4))) float f32x4;
typedef __attribute__((ext_vector_type(16))) float f32x16;

#define SEQ   8192
#define DEM   256
#define CHUNK 512
#define NTASKS 272      // sum over 32 qtiles (256 rows) of (q>>1)+1

#define GLOAD_LDS16(g, l) \
  __builtin_amdgcn_global_load_lds((const __attribute__((address_space(1))) void*)(g), \
                                   (__attribute__((address_space(3))) void*)(l), 16, 0, 0)

static __device__ __forceinline__ unsigned short f2bf(float f) {
  union { float f; unsigned int u; } v; v.f = f;
  return (unsigned short)((v.u + 0x7fffu + ((v.u >> 16) & 1u)) >> 16);
}
static __device__ __forceinline__ float bf2f(unsigned short h) {
  union { unsigned int u; float f; } v; v.u = ((unsigned int)h) << 16;
  return v.f;
}
static __device__ __forceinline__ unsigned cvt_pk_bf16(float lo, float hi) {
  unsigned r;
  asm("v_cvt_pk_bf16_f32 %0, %1, %2" : "=v"(r) : "v"(lo), "v"(hi));
  return r;
}
// after swap: h0 holds (for every lane) the value computed by the hi=0 lane of
// the same ql; h1 holds the hi=1 lane's value.
static __device__ __forceinline__ void swap32(unsigned &h0, unsigned &h1, unsigned x) {
  unsigned a = x, b = x;
  asm volatile("v_permlane32_swap_b32 %0, %1" : "+v"(a), "+v"(b));
  h0 = a; h1 = b;
}

// ---- projections: qb[s][d] = (log2e/16)*sum_e x[s][e] Wq[d][e];
//      kb[s][d] = sum_e x[s][e] Wk[d][e]; vtb[d][s] = sum_e x[s][e] Wv[d][e]
__global__ __launch_bounds__(256) void proj_kernel(
    const float* __restrict__ x,  const float* __restrict__ Wq,
    const float* __restrict__ Wk, const float* __restrict__ Wv,
    unsigned short* __restrict__ qb, unsigned short* __restrict__ kb,
    unsigned short* __restrict__ vtb)
{
  const int m0 = blockIdx.x * 128;
  const int n0 = blockIdx.y * 128;
  const int which = blockIdx.z;
  const float* __restrict__ W = (which == 0) ? Wq : (which == 1) ? Wk : Wv;

  __shared__ unsigned short As[128 * 64];
  __shared__ unsigned short Bs[128 * 64];

  const int tid  = threadIdx.x;
  const int wave = tid >> 6, lane = tid & 63;
  const int wm = wave >> 1, wn = wave & 1;
  const int lr = lane & 15, lg = lane >> 4;

  f32x4 acc[4][4];
  #pragma unroll
  for (int i = 0; i < 4; i++)
    #pragma unroll
    for (int j = 0; j < 4; j++) acc[i][j] = (f32x4){0.f, 0.f, 0.f, 0.f};

  for (int k0 = 0; k0 < DEM; k0 += 64) {
    __syncthreads();
    #pragma unroll
    for (int p = 0; p < 8; p++) {
      int c   = p * 256 + tid;
      int row = c >> 4;
      int col = (c & 15) << 2;
      float4 fA = *reinterpret_cast<const float4*>(&x[(m0 + row) * DEM + k0 + col]);
      float4 fB = *reinterpret_cast<const float4*>(&W[(n0 + row) * DEM + k0 + col]);
      uint2 hA, hB;
      hA.x = f2bf(fA.x) | ((unsigned)f2bf(fA.y) << 16);
      hA.y = f2bf(fA.z) | ((unsigned)f2bf(fA.w) << 16);
      hB.x = f2bf(fB.x) | ((unsigned)f2bf(fB.y) << 16);
      hB.y = f2bf(fB.z) | ((unsigned)f2bf(fB.w) << 16);
      int byte = (row * 128 + (col << 1)) ^ ((row & 7) << 4);
      *reinterpret_cast<uint2*>(reinterpret_cast<char*>(As) + byte) = hA;
      *reinterpret_cast<uint2*>(reinterpret_cast<char*>(Bs) + byte) = hB;
    }
    __syncthreads();

    #pragma unroll
    for (int ks = 0; ks < 2; ks++) {
      bf16x8 a[4], b[4];
      #pragma unroll
      for (int mt = 0; mt < 4; mt++) {
        int row  = wm * 64 + mt * 16 + lr;
        int byte = (row * 128 + ks * 64 + lg * 16) ^ ((row & 7) << 4);
        a[mt] = *reinterpret_cast<const bf16x8*>(reinterpret_cast<const char*>(As) + byte);
      }
      #pragma unroll
      for (int nt = 0; nt < 4; nt++) {
        int row  = wn * 64 + nt * 16 + lr;
        int byte = (row * 128 + ks * 64 + lg * 16) ^ ((row & 7) << 4);
        b[nt] = *reinterpret_cast<const bf16x8*>(reinterpret_cast<const char*>(Bs) + byte);
      }
      #pragma unroll
      for (int mt = 0; mt < 4; mt++)
        #pragma unroll
        for (int nt = 0; nt < 4; nt++)
          acc[mt][nt] = __builtin_amdgcn_mfma_f32_16x16x32_bf16(a[mt], b[nt], acc[mt][nt], 0, 0, 0);
    }
  }

  const float osc = (which == 0) ? 0.0625f * 1.4426950408889634f : 1.0f;
  #pragma unroll
  for (int mt = 0; mt < 4; mt++)
    #pragma unroll
    for (int nt = 0; nt < 4; nt++)
      #pragma unroll
      for (int r = 0; r < 4; r++) {
        int row = m0 + wm * 64 + mt * 16 + lg * 4 + r;
        int col = n0 + wn * 64 + nt * 16 + lr;
        unsigned short h = f2bf(acc[mt][nt][r] * osc);
        if (which == 0)      qb[row * DEM + col]  = h;
        else if (which == 1) kb[row * DEM + col]  = h;
        else                 vtb[(size_t)col * SEQ + row] = h;
      }
}

// ---- attention: task = (qtile 256 rows, kv chunk <=512). 8 waves x 32 q-rows.
// 32x32x16 MFMA, swapped operands. K LDS [64x512B] swz (row&31)<<4 (32-way spread);
// V LDS [128x256B] (2 d-rows per LDS row) swz (row&15)<<4 (2-way, free).
// P stays in registers: cvt_pk + permlane32_swap + hi-select (T12).
// 2-raw-barrier counted-vmcnt pipeline (T4): no vmcnt(0) drain in loop.
__global__ __launch_bounds__(512, 2) void attn_kernel(
    const unsigned short* __restrict__ qb, const unsigned short* __restrict__ kb,
    const unsigned short* __restrict__ vtb,
    unsigned short* __restrict__ pOb, float* __restrict__ ml)
{
  __shared__ char lds[131072];
  char* Ks = lds;               // 2 x 32KB K tiles
  char* Vs = lds + 65536;       // 2 x 32KB V tiles

  const int t = NTASKS - 1 - (int)blockIdx.x;   // largest q first
  int q = 0, s = 0;
  for (;;) { int n = (q >> 1) + 1; if (t < s + n) break; s += n; ++q; }
  const int c = t - s;
  const int kv_lo = c * CHUNK;
  const int kv_hi_blk = min(kv_lo + CHUNK, (q + 1) * 256);

  const int tid = threadIdx.x;
  const int wave = tid >> 6, lane = tid & 63;
  const int ql = lane & 31;
  const int hi = lane >> 5;
  const bool hib = hi != 0;
  const int qrow = q * 256 + wave * 32;
  const int kv_hi_w = min(kv_hi_blk, ((qrow + 32 + 63) >> 6) << 6);

  const char* kb_c  = (const char*)kb;
  const char* vtb_c = (const char*)vtb;

  // ---- Q fragments hoisted (B-operand: col=ql, k = i*16 + hi*8 + j)
  bf16x8 qf[16];
  {
    const unsigned short* qp = qb + (size_t)(qrow + ql) * DEM + hi * 8;
    #pragma unroll
    for (int i = 0; i < 16; i++) qf[i] = *reinterpret_cast<const bf16x8*>(qp + i * 16);
  }

  f32x16 o[8];   // O^T: o[dt][rg] -> q=ql, d = dt*32 + (rg&3)+8*(rg>>2)+4*hi
  #pragma unroll
  for (int dt = 0; dt < 8; dt++)
    #pragma unroll
    for (int rg = 0; rg < 16; rg++) o[dt][rg] = 0.f;
  float m_run = -3.0e38f, l_run = 0.f;   // per-lane, q = qrow + ql (log2 domain)

  // ---- staging helper: K [64x512B] swz row&31; V [128x256B] row=d>>1 swz row&15
  auto stage = [&](int kvt, char* kdst, char* vdst) {
    #pragma unroll
    for (int i = 0; i < 4; i++) {
      int sl = i * 8192 + tid * 16;
      int krow = sl >> 9;
      int kin  = (sl & 511) ^ ((krow & 31) << 4);
      GLOAD_LDS16(kb_c + (((size_t)(kvt + krow)) << 9) + kin,
                  kdst + i * 8192 + (wave << 10));
      int vrow = sl >> 8;
      int s_in = ((sl >> 4) & 15) ^ (vrow & 15);
      int vd   = 2 * vrow + (s_in >> 3);
      int vkb  = (s_in & 7) << 4;
      GLOAD_LDS16(vtb_c + (size_t)vd * (SEQ * 2) + (size_t)kvt * 2 + vkb,
                  vdst + i * 8192 + (wave << 10));
    }
  };

  stage(kv_lo, Ks, Vs);    // prologue: tile 0 into buf 0

  const int nsteps = (kv_hi_blk - kv_lo) >> 6;
  for (int st = 0; st < nsteps; st++) {
    const int kv0 = kv_lo + (st << 6);
    const int buf = st & 1;

    asm volatile("s_waitcnt lgkmcnt(0)" ::: "memory");
    __builtin_amdgcn_s_barrier();                      // BAR1: buf^1 reads done
    if (st + 1 < nsteps) {
      stage(kv0 + 64, Ks + (buf ^ 1) * 32768, Vs + (buf ^ 1) * 32768);
      asm volatile("s_waitcnt vmcnt(8)" ::: "memory"); // own stage(t) landed
    } else {
      asm volatile("s_waitcnt vmcnt(0)" ::: "memory");
    }
    __builtin_amdgcn_s_barrier();                      // BAR2: whole tile ready
    __builtin_amdgcn_sched_barrier(0);

    if (kv0 < kv_hi_w) {
      // ---- QK^T swapped: A=K rows (kv), B=Q cols (q=ql)
      f32x16 sc0, sc1;
      #pragma unroll
      for (int rg = 0; rg < 16; rg++) { sc0[rg] = 0.f; sc1[rg] = 0.f; }
      const char* kbase = Ks + buf * 32768;
      const int rsw = ql << 4;
      __builtin_amdgcn_s_setprio(1);
      #pragma unroll
      for (int i = 0; i < 16; i++) {
        int off = (i * 32 + hi * 16) ^ rsw;
        bf16x8 kf0 = *reinterpret_cast<const bf16x8*>(kbase + ql * 512 + off);
        bf16x8 kf1 = *reinterpret_cast<const bf16x8*>(kbase + (32 + ql) * 512 + off);
        sc0 = __builtin_amdgcn_mfma_f32_32x32x16_bf16(kf0, qf[i], sc0, 0, 0, 0);
        sc1 = __builtin_amdgcn_mfma_f32_32x32x16_bf16(kf1, qf[i], sc1, 0, 0, 0);
      }
      __builtin_amdgcn_s_setprio(0);

      // ---- mask + per-lane online softmax (log2 domain), q = qrow + ql
      const int qg = qrow + ql;
      if (kv0 + 63 > qrow) {
        #pragma unroll
        for (int rg = 0; rg < 16; rg++) {
          int kvp = kv0 + (rg & 3) + 8 * (rg >> 2) + 4 * hi;
          if (kvp      > qg) sc0[rg] = -3.0e38f;
          if (kvp + 32 > qg) sc1[rg] = -3.0e38f;
        }
      }
      float mx[8];
      #pragma unroll
      for (int j = 0; j < 8; j++) mx[j] = fmaxf(sc0[j], fmaxf(sc0[j + 8], fmaxf(sc1[j], sc1[j + 8])));
      #pragma unroll
      for (int j = 0; j < 4; j++) mx[j] = fmaxf(mx[j], mx[j + 4]);
      float pmax = fmaxf(fmaxf(mx[0], mx[1]), fmaxf(mx[2], mx[3]));
      pmax = fmaxf(pmax, __shfl_xor(pmax, 32));

      const bool defer = __all(pmax <= m_run + 11.0f);   // T13
      float mnew = m_run;
      if (!defer) {
        mnew = fmaxf(m_run, pmax);
        const float cr = __builtin_amdgcn_exp2f(m_run - mnew);
        #pragma unroll
        for (int dt = 0; dt < 8; dt++)
          #pragma unroll
          for (int rg = 0; rg < 16; rg++) o[dt][rg] *= cr;
        l_run *= cr;
        m_run = mnew;
      }

      // ---- exp2 + pack + half-swap: P fragments entirely in registers
      unsigned h0v[2][4][2], h1v[2][4][2];
      float sum = 0.f;
      #pragma unroll
      for (int a = 0; a < 4; a++) {
        float e0 = __builtin_amdgcn_exp2f(sc0[4*a+0] - mnew);
        float e1 = __builtin_amdgcn_exp2f(sc0[4*a+1] - mnew);
        float e2 = __builtin_amdgcn_exp2f(sc0[4*a+2] - mnew);
        float e3 = __builtin_amdgcn_exp2f(sc0[4*a+3] - mnew);
        float f0 = __builtin_amdgcn_exp2f(sc1[4*a+0] - mnew);
        float f1 = __builtin_amdgcn_exp2f(sc1[4*a+1] - mnew);
        float f2 = __builtin_amdgcn_exp2f(sc1[4*a+2] - mnew);
        float f3 = __builtin_amdgcn_exp2f(sc1[4*a+3] - mnew);
        sum += ((e0 + e1) + (e2 + e3)) + ((f0 + f1) + (f2 + f3));
        swap32(h0v[0][a][0], h1v[0][a][0], cvt_pk_bf16(e0, e1));
        swap32(h0v[0][a][1], h1v[0][a][1], cvt_pk_bf16(e2, e3));
        swap32(h0v[1][a][0], h1v[1][a][0], cvt_pk_bf16(f0, f1));
        swap32(h0v[1][a][1], h1v[1][a][1], cvt_pk_bf16(f2, f3));
      }
      sum += __shfl_xor(sum, 32);
      l_run += sum;

      // ---- PV: O^T += V^T x P^T, P B-fragment assembled from swapped halves
      const char* vbase = Vs + buf * 32768;
      const int vrl = ql >> 1;
      __builtin_amdgcn_s_setprio(1);
      #pragma unroll
      for (int s16 = 0; s16 < 4; s16++) {
        const int sub = s16 >> 1, tt = s16 & 1;
        union { unsigned u[4]; bf16x8 v; } pf;
        pf.u[0] = hib ? h0v[sub][2*tt+1][0] : h0v[sub][2*tt][0];
        pf.u[1] = hib ? h0v[sub][2*tt+1][1] : h0v[sub][2*tt][1];
        pf.u[2] = hib ? h1v[sub][2*tt+1][0] : h1v[sub][2*tt][0];
        pf.u[3] = hib ? h1v[sub][2*tt+1][1] : h1v[sub][2*tt][1];
        const int slot = (((ql & 1) << 3) | (s16 << 1) | hi) ^ vrl;
        #pragma unroll
        for (int dt = 0; dt < 8; dt++) {
          bf16x8 vf = *reinterpret_cast<const bf16x8*>(
              vbase + (dt * 16 + vrl) * 256 + slot * 16);
          o[dt] = __builtin_amdgcn_mfma_f32_32x32x16_bf16(vf, pf.v, o[dt], 0, 0, 0);
        }
      }
      __builtin_amdgcn_s_setprio(0);
    }
  }

  // ---- write partials: q=ql, d = dt*32 + tq*8 + hi*4 + (0..3)
  const size_t obase = (size_t)t * (256 * 256);
  const int row_l = wave * 32 + ql;
  #pragma unroll
  for (int dt = 0; dt < 8; dt++)
    #pragma unroll
    for (int tq = 0; tq < 4; tq++) {
      const int d = dt * 32 + tq * 8 + hi * 4;
      uint2 w;
      w.x = cvt_pk_bf16(o[dt][tq*4+0], o[dt][tq*4+1]);
      w.y = cvt_pk_bf16(o[dt][tq*4+2], o[dt][tq*4+3]);
      *reinterpret_cast<uint2*>(&pOb[obase + (size_t)row_l * 256 + d]) = w;
    }
  if (hi == 0) {
    ml[(size_t)t * 512 + row_l * 2]     = m_run;
    ml[(size_t)t * 512 + row_l * 2 + 1] = l_run;
  }
}

// ---- merge partials (log2-domain m)
__global__ __launch_bounds__(256) void merge_kernel(
    const unsigned short* __restrict__ pOb, const float* __restrict__ ml,
    float* __restrict__ out)
{
  const int tid = threadIdx.x;
  const int row = blockIdx.x * 32 + (tid >> 3);
  const int c0  = (tid & 7) * 32;
  const int q = row >> 8;              // 256-row qtile, 0..31
  const int a = q >> 1, b = q & 1;
  const int n = a + 1;
  const int base = (a + b) * (a + 1);
  const int lrow = row & 255;

  float M = -3.0e38f;
  for (int i = 0; i < n; i++)
    M = fmaxf(M, ml[(size_t)(base + i) * 512 + lrow * 2]);

  float L = 0.f;
  float acc[32];
  #pragma unroll
  for (int j = 0; j < 32; j++) acc[j] = 0.f;

  for (int i = 0; i < n; i++) {
    const float mi = ml[(size_t)(base + i) * 512 + lrow * 2];
    const float li = ml[(size_t)(base + i) * 512 + lrow * 2 + 1];
    const float fi = __builtin_amdgcn_exp2f(mi - M);
    L += li * fi;
    const unsigned short* src = pOb + (size_t)(base + i) * (256 * 256) + (size_t)lrow * 256 + c0;
    #pragma unroll
    for (int v = 0; v < 4; v++) {
      u16x8 u = *reinterpret_cast<const u16x8*>(src + v * 8);
      #pragma unroll
      for (int j = 0; j < 8; j++) acc[v * 8 + j] += bf2f((unsigned short)u[j]) * fi;
    }
  }
  const float inv = 1.f / L;
  #pragma unroll
  for (int v = 0; v < 8; v++) {
    float4 w;
    w.x = acc[v * 4 + 0] * inv; w.y = acc[v * 4 + 1] * inv;
    w.z = acc[v * 4 + 2] * inv; w.w = acc[v * 4 + 3] * inv;
    *reinterpret_cast<float4*>(&out[(size_t)row * 256 + c0 + v * 4]) = w;
  }
}

extern "C" void kernel_launch(void* const* d_in, const int* in_sizes, int n_in,
                              void* d_out, int out_size, void* d_ws, size_t ws_size,
                              hipStream_t stream)
{
  const float* x  = (const float*)d_in[0];
  const float* Wq = (const float*)d_in[1];
  const float* Wk = (const float*)d_in[2];
  const float* Wv = (const float*)d_in[3];

  char* ws = (char*)d_ws;
  unsigned short* qb  = (unsigned short*)ws;                              // 4 MB
  unsigned short* kb  = (unsigned short*)(ws + (size_t)4  * 1024 * 1024); // 4 MB
  unsigned short* vtb = (unsigned short*)(ws + (size_t)8  * 1024 * 1024); // 4 MB
  float*          ml  = (float*)         (ws + (size_t)12 * 1024 * 1024); // 544 KB
  unsigned short* pOb = (unsigned short*)(ws + (size_t)13 * 1024 * 1024); // 35.7 MB

  proj_kernel<<<dim3(64, 2, 3), 256, 0, stream>>>(x, Wq, Wk, Wv, qb, kb, vtb);
  attn_kernel<<<dim3(NTASKS), 512, 0, stream>>>(qb, kb, vtb, pOb, ml);
  merge_kernel<<<dim3(SEQ / 32), 256, 0, stream>>>(pOb, ml, (float*)d_out);
}

// Round 11
// 134.473 us; speedup vs baseline: 1.2683x; 1.2583x over previous
//
#include <hip/hip_runtime.h>
#include <hip/hip_bf16.h>

typedef __attribute__((ext_vector_type(8))) short bf16x8;
typedef __attribute__((ext_vector_type(8))) unsigned short u16x8;
typedef __attribute__((ext_vector_type(4))) float f32x4;
typedef __attribute__((ext_vector_type(16))) float f32x16;

#define SEQ   8192
#define DEM   256
#define NTASKS 256

// chunks per 256-row qtile (sum = 256, every chunk 4..9 steps of 64 kv)
__device__ __constant__ int NTAB[32] = {
  1,1,2,2,3,3,4,4,4,5,5,6,6,7,7,8,
  8,8,9,9,10,10,11,11,12,13,13,14,14,15,15,16};
__device__ __constant__ int PTAB[33] = {
  0,1,2,4,6,9,12,16,20,24,29,34,40,46,53,60,68,
  76,84,93,102,112,122,133,144,156,169,182,196,210,225,240,256};

#define GLOAD_LDS16(g, l) \
  __builtin_amdgcn_global_load_lds((const __attribute__((address_space(1))) void*)(g), \
                                   (__attribute__((address_space(3))) void*)(l), 16, 0, 0)

static __device__ __forceinline__ unsigned short f2bf(float f) {
  union { float f; unsigned int u; } v; v.f = f;
  return (unsigned short)((v.u + 0x7fffu + ((v.u >> 16) & 1u)) >> 16);
}
static __device__ __forceinline__ float bf2f(unsigned short h) {
  union { unsigned int u; float f; } v; v.u = ((unsigned int)h) << 16;
  return v.f;
}
static __device__ __forceinline__ unsigned cvt_pk_bf16(float lo, float hi) {
  unsigned r;
  asm("v_cvt_pk_bf16_f32 %0, %1, %2" : "=v"(r) : "v"(lo), "v"(hi));
  return r;
}
// after swap: h0 holds (for every lane) the value from the hi=0 lane of the
// same ql; h1 holds the hi=1 lane's value. (Proven in R9 on cvt_pk outputs.)
static __device__ __forceinline__ void swap32(unsigned &h0, unsigned &h1, unsigned x) {
  unsigned a = x, b = x;
  asm volatile("v_permlane32_swap_b32 %0, %1" : "+v"(a), "+v"(b));
  h0 = a; h1 = b;
}

// ---- projections: qb[s][d] = (log2e/16)*sum_e x[s][e] Wq[d][e];
//      kb[s][d] = sum_e x[s][e] Wk[d][e]; vtb[d][s] = sum_e x[s][e] Wv[d][e]
__global__ __launch_bounds__(256) void proj_kernel(
    const float* __restrict__ x,  const float* __restrict__ Wq,
    const float* __restrict__ Wk, const float* __restrict__ Wv,
    unsigned short* __restrict__ qb, unsigned short* __restrict__ kb,
    unsigned short* __restrict__ vtb)
{
  const int m0 = blockIdx.x * 128;
  const int n0 = blockIdx.y * 128;
  const int which = blockIdx.z;
  const float* __restrict__ W = (which == 0) ? Wq : (which == 1) ? Wk : Wv;

  __shared__ unsigned short As[128 * 64];
  __shared__ unsigned short Bs[128 * 64];

  const int tid  = threadIdx.x;
  const int wave = tid >> 6, lane = tid & 63;
  const int wm = wave >> 1, wn = wave & 1;
  const int lr = lane & 15, lg = lane >> 4;

  f32x4 acc[4][4];
  #pragma unroll
  for (int i = 0; i < 4; i++)
    #pragma unroll
    for (int j = 0; j < 4; j++) acc[i][j] = (f32x4){0.f, 0.f, 0.f, 0.f};

  for (int k0 = 0; k0 < DEM; k0 += 64) {
    __syncthreads();
    #pragma unroll
    for (int p = 0; p < 8; p++) {
      int c   = p * 256 + tid;
      int row = c >> 4;
      int col = (c & 15) << 2;
      float4 fA = *reinterpret_cast<const float4*>(&x[(m0 + row) * DEM + k0 + col]);
      float4 fB = *reinterpret_cast<const float4*>(&W[(n0 + row) * DEM + k0 + col]);
      uint2 hA, hB;
      hA.x = f2bf(fA.x) | ((unsigned)f2bf(fA.y) << 16);
      hA.y = f2bf(fA.z) | ((unsigned)f2bf(fA.w) << 16);
      hB.x = f2bf(fB.x) | ((unsigned)f2bf(fB.y) << 16);
      hB.y = f2bf(fB.z) | ((unsigned)f2bf(fB.w) << 16);
      int byte = (row * 128 + (col << 1)) ^ ((row & 7) << 4);
      *reinterpret_cast<uint2*>(reinterpret_cast<char*>(As) + byte) = hA;
      *reinterpret_cast<uint2*>(reinterpret_cast<char*>(Bs) + byte) = hB;
    }
    __syncthreads();

    #pragma unroll
    for (int ks = 0; ks < 2; ks++) {
      bf16x8 a[4], b[4];
      #pragma unroll
      for (int mt = 0; mt < 4; mt++) {
        int row  = wm * 64 + mt * 16 + lr;
        int byte = (row * 128 + ks * 64 + lg * 16) ^ ((row & 7) << 4);
        a[mt] = *reinterpret_cast<const bf16x8*>(reinterpret_cast<const char*>(As) + byte);
      }
      #pragma unroll
      for (int nt = 0; nt < 4; nt++) {
        int row  = wn * 64 + nt * 16 + lr;
        int byte = (row * 128 + ks * 64 + lg * 16) ^ ((row & 7) << 4);
        b[nt] = *reinterpret_cast<const bf16x8*>(reinterpret_cast<const char*>(Bs) + byte);
      }
      #pragma unroll
      for (int mt = 0; mt < 4; mt++)
        #pragma unroll
        for (int nt = 0; nt < 4; nt++)
          acc[mt][nt] = __builtin_amdgcn_mfma_f32_16x16x32_bf16(a[mt], b[nt], acc[mt][nt], 0, 0, 0);
    }
  }

  const float osc = (which == 0) ? 0.0625f * 1.4426950408889634f : 1.0f;
  #pragma unroll
  for (int mt = 0; mt < 4; mt++)
    #pragma unroll
    for (int nt = 0; nt < 4; nt++)
      #pragma unroll
      for (int r = 0; r < 4; r++) {
        int row = m0 + wm * 64 + mt * 16 + lg * 4 + r;
        int col = n0 + wn * 64 + nt * 16 + lr;
        unsigned short h = f2bf(acc[mt][nt][r] * osc);
        if (which == 0)      qb[row * DEM + col]  = h;
        else if (which == 1) kb[row * DEM + col]  = h;
        else                 vtb[(size_t)col * SEQ + row] = h;
      }
}

// ---- attention: 256 balanced tasks (1 per CU), task = (qtile 256 rows, 4..9
// steps of 64 kv). 8 waves x 32 q-rows, 32x32x16 MFMA, swapped operands,
// in-register P (cvt_pk + permlane32_swap), counted-vmcnt 2-barrier pipeline.
// pmax/sum cross-half reductions via __shfl_xor (proven; permlane-on-VALU
// results suspected hazard -> R10 failure).
__global__ __launch_bounds__(512, 2) void attn_kernel(
    const unsigned short* __restrict__ qb, const unsigned short* __restrict__ kb,
    const unsigned short* __restrict__ vtb,
    unsigned short* __restrict__ pOb, float* __restrict__ ml)
{
  __shared__ char lds[131072];
  char* Ks = lds;               // 2 x 32KB K tiles [64 kv x 512B] swz (row&31)<<4
  char* Vs = lds + 65536;       // 2 x 32KB V tiles [128 rows x 256B] swz (row&15)<<4

  // ---- balanced task decode
  const int t = (int)blockIdx.x;
  int q = 0;
  while (t >= PTAB[q + 1]) ++q;
  const int c = t - PTAB[q];
  const int T4 = (q + 1) * 4, n = NTAB[q];
  const int bs = T4 / n, rr = T4 % n;
  const int steps = bs + (c < rr ? 1 : 0);
  const int start = c * bs + min(c, rr);
  const int kv_lo = start << 6;
  const int kv_hi_blk = kv_lo + (steps << 6);

  const int tid = threadIdx.x;
  const int wave = tid >> 6, lane = tid & 63;
  const int ql = lane & 31;
  const int hi = lane >> 5;
  const bool hib = hi != 0;
  const int qrow = q * 256 + wave * 32;
  const int kv_hi_w = min(kv_hi_blk, ((qrow + 32 + 63) >> 6) << 6);

  const char* kb_c  = (const char*)kb;
  const char* vtb_c = (const char*)vtb;

  // ---- Q fragments hoisted (B-operand: col=ql, k = i*16 + hi*8 + j)
  bf16x8 qf[16];
  {
    const unsigned short* qp = qb + (size_t)(qrow + ql) * DEM + hi * 8;
    #pragma unroll
    for (int i = 0; i < 16; i++) qf[i] = *reinterpret_cast<const bf16x8*>(qp + i * 16);
  }

  f32x16 o[8];   // O^T: o[dt][rg] -> q=ql, d = dt*32 + (rg&3)+8*(rg>>2)+4*hi
  #pragma unroll
  for (int dt = 0; dt < 8; dt++)
    #pragma unroll
    for (int rg = 0; rg < 16; rg++) o[dt][rg] = 0.f;
  float m_run = -3.0e38f, l_run = 0.f;   // per-lane, q = qrow + ql (log2 domain)

  // ---- staging: K [64x512B] swz row&31; V [128x256B] row=d>>1 swz row&15
  auto stage = [&](int kvt, char* kdst, char* vdst) {
    #pragma unroll
    for (int i = 0; i < 4; i++) {
      int sl = i * 8192 + tid * 16;
      int krow = sl >> 9;
      int kin  = (sl & 511) ^ ((krow & 31) << 4);
      GLOAD_LDS16(kb_c + (((size_t)(kvt + krow)) << 9) + kin,
                  kdst + i * 8192 + (wave << 10));
      int vrow = sl >> 8;
      int s_in = ((sl >> 4) & 15) ^ (vrow & 15);
      int vd   = 2 * vrow + (s_in >> 3);
      int vkb  = (s_in & 7) << 4;
      GLOAD_LDS16(vtb_c + (size_t)vd * (SEQ * 2) + (size_t)kvt * 2 + vkb,
                  vdst + i * 8192 + (wave << 10));
    }
  };

  stage(kv_lo, Ks, Vs);    // prologue: tile 0 into buf 0

  const int nsteps = steps;
  for (int st = 0; st < nsteps; st++) {
    const int kv0 = kv_lo + (st << 6);
    const int buf = st & 1;

    asm volatile("s_waitcnt lgkmcnt(0)" ::: "memory");
    __builtin_amdgcn_s_barrier();                      // BAR1: buf^1 reads done
    if (st + 1 < nsteps) {
      stage(kv0 + 64, Ks + (buf ^ 1) * 32768, Vs + (buf ^ 1) * 32768);
      asm volatile("s_waitcnt vmcnt(8)" ::: "memory"); // own stage(t) landed
    } else {
      asm volatile("s_waitcnt vmcnt(0)" ::: "memory");
    }
    __builtin_amdgcn_s_barrier();                      // BAR2: whole tile ready
    __builtin_amdgcn_sched_barrier(0);

    if (kv0 < kv_hi_w) {
      // ---- QK^T swapped: A=K rows (kv), B=Q cols (q=ql)
      f32x16 sc0, sc1;
      #pragma unroll
      for (int rg = 0; rg < 16; rg++) { sc0[rg] = 0.f; sc1[rg] = 0.f; }
      const char* kbase = Ks + buf * 32768;
      const int rsw = ql << 4;
      __builtin_amdgcn_s_setprio(1);
      #pragma unroll
      for (int i = 0; i < 16; i++) {
        int off = (i * 32 + hi * 16) ^ rsw;
        bf16x8 kf0 = *reinterpret_cast<const bf16x8*>(kbase + ql * 512 + off);
        bf16x8 kf1 = *reinterpret_cast<const bf16x8*>(kbase + (32 + ql) * 512 + off);
        sc0 = __builtin_amdgcn_mfma_f32_32x32x16_bf16(kf0, qf[i], sc0, 0, 0, 0);
        sc1 = __builtin_amdgcn_mfma_f32_32x32x16_bf16(kf1, qf[i], sc1, 0, 0, 0);
      }
      __builtin_amdgcn_s_setprio(0);

      // ---- mask + per-lane online softmax (log2 domain), q = qrow + ql
      const int qg = qrow + ql;
      if (kv0 + 63 > qrow) {
        #pragma unroll
        for (int rg = 0; rg < 16; rg++) {
          int kvp = kv0 + (rg & 3) + 8 * (rg >> 2) + 4 * hi;
          if (kvp      > qg) sc0[rg] = -3.0e38f;
          if (kvp + 32 > qg) sc1[rg] = -3.0e38f;
        }
      }
      float mx[8];
      #pragma unroll
      for (int j = 0; j < 8; j++) mx[j] = fmaxf(sc0[j], fmaxf(sc0[j + 8], fmaxf(sc1[j], sc1[j + 8])));
      #pragma unroll
      for (int j = 0; j < 4; j++) mx[j] = fmaxf(mx[j], mx[j + 4]);
      float pmax = fmaxf(fmaxf(mx[0], mx[1]), fmaxf(mx[2], mx[3]));
      pmax = fmaxf(pmax, __shfl_xor(pmax, 32));

      const bool defer = __all(pmax <= m_run + 11.0f);   // T13
      float mnew = m_run;
      if (!defer) {
        mnew = fmaxf(m_run, pmax);
        const float cr = __builtin_amdgcn_exp2f(m_run - mnew);
        #pragma unroll
        for (int dt = 0; dt < 8; dt++)
          #pragma unroll
          for (int rg = 0; rg < 16; rg++) o[dt][rg] *= cr;
        l_run *= cr;
        m_run = mnew;
      }

      // ---- exp2 + pack + half-swap: P fragments entirely in registers
      unsigned h0v[2][4][2], h1v[2][4][2];
      float sum = 0.f;
      #pragma unroll
      for (int a = 0; a < 4; a++) {
        float e0 = __builtin_amdgcn_exp2f(sc0[4*a+0] - mnew);
        float e1 = __builtin_amdgcn_exp2f(sc0[4*a+1] - mnew);
        float e2 = __builtin_amdgcn_exp2f(sc0[4*a+2] - mnew);
        float e3 = __builtin_amdgcn_exp2f(sc0[4*a+3] - mnew);
        float f0 = __builtin_amdgcn_exp2f(sc1[4*a+0] - mnew);
        float f1 = __builtin_amdgcn_exp2f(sc1[4*a+1] - mnew);
        float f2 = __builtin_amdgcn_exp2f(sc1[4*a+2] - mnew);
        float f3 = __builtin_amdgcn_exp2f(sc1[4*a+3] - mnew);
        sum += ((e0 + e1) + (e2 + e3)) + ((f0 + f1) + (f2 + f3));
        swap32(h0v[0][a][0], h1v[0][a][0], cvt_pk_bf16(e0, e1));
        swap32(h0v[0][a][1], h1v[0][a][1], cvt_pk_bf16(e2, e3));
        swap32(h0v[1][a][0], h1v[1][a][0], cvt_pk_bf16(f0, f1));
        swap32(h0v[1][a][1], h1v[1][a][1], cvt_pk_bf16(f2, f3));
      }
      sum += __shfl_xor(sum, 32);
      l_run += sum;

      // ---- PV: O^T += V^T x P^T, P B-fragment assembled from swapped halves
      const char* vbase = Vs + buf * 32768;
      const int vrl = ql >> 1;
      __builtin_amdgcn_s_setprio(1);
      #pragma unroll
      for (int s16 = 0; s16 < 4; s16++) {
        const int sub = s16 >> 1, tt = s16 & 1;
        union { unsigned u[4]; bf16x8 v; } pf;
        pf.u[0] = hib ? h0v[sub][2*tt+1][0] : h0v[sub][2*tt][0];
        pf.u[1] = hib ? h0v[sub][2*tt+1][1] : h0v[sub][2*tt][1];
        pf.u[2] = hib ? h1v[sub][2*tt+1][0] : h1v[sub][2*tt][0];
        pf.u[3] = hib ? h1v[sub][2*tt+1][1] : h1v[sub][2*tt][1];
        const int slot = (((ql & 1) << 3) | (s16 << 1) | hi) ^ vrl;
        #pragma unroll
        for (int dt = 0; dt < 8; dt++) {
          bf16x8 vf = *reinterpret_cast<const bf16x8*>(
              vbase + (dt * 16 + vrl) * 256 + slot * 16);
          o[dt] = __builtin_amdgcn_mfma_f32_32x32x16_bf16(vf, pf.v, o[dt], 0, 0, 0);
        }
      }
      __builtin_amdgcn_s_setprio(0);
    }
  }

  // ---- write partials: q=ql, d = dt*32 + tq*8 + hi*4 + (0..3)
  const size_t obase = (size_t)t * (256 * 256);
  const int row_l = wave * 32 + ql;
  #pragma unroll
  for (int dt = 0; dt < 8; dt++)
    #pragma unroll
    for (int tq = 0; tq < 4; tq++) {
      const int d = dt * 32 + tq * 8 + hi * 4;
      uint2 w;
      w.x = cvt_pk_bf16(o[dt][tq*4+0], o[dt][tq*4+1]);
      w.y = cvt_pk_bf16(o[dt][tq*4+2], o[dt][tq*4+3]);
      *reinterpret_cast<uint2*>(&pOb[obase + (size_t)row_l * 256 + d]) = w;
    }
  if (hi == 0) {
    ml[(size_t)t * 512 + row_l * 2]     = m_run;
    ml[(size_t)t * 512 + row_l * 2 + 1] = l_run;
  }
}

// ---- merge partials (log2-domain m)
__global__ __launch_bounds__(256) void merge_kernel(
    const unsigned short* __restrict__ pOb, const float* __restrict__ ml,
    float* __restrict__ out)
{
  const int tid = threadIdx.x;
  const int row = blockIdx.x * 32 + (tid >> 3);
  const int c0  = (tid & 7) * 32;
  const int q = row >> 8;              // 256-row qtile, 0..31
  const int n = NTAB[q];
  const int base = PTAB[q];
  const int lrow = row & 255;

  float M = -3.0e38f;
  for (int i = 0; i < n; i++)
    M = fmaxf(M, ml[(size_t)(base + i) * 512 + lrow * 2]);

  float L = 0.f;
  float acc[32];
  #pragma unroll
  for (int j = 0; j < 32; j++) acc[j] = 0.f;

  for (int i = 0; i < n; i++) {
    const float mi = ml[(size_t)(base + i) * 512 + lrow * 2];
    const float li = ml[(size_t)(base + i) * 512 + lrow * 2 + 1];
    const float fi = __builtin_amdgcn_exp2f(mi - M);
    L += li * fi;
    const unsigned short* src = pOb + (size_t)(base + i) * (256 * 256) + (size_t)lrow * 256 + c0;
    #pragma unroll
    for (int v = 0; v < 4; v++) {
      u16x8 u = *reinterpret_cast<const u16x8*>(src + v * 8);
      #pragma unroll
      for (int j = 0; j < 8; j++) acc[v * 8 + j] += bf2f((unsigned short)u[j]) * fi;
    }
  }
  const float inv = 1.f / L;
  #pragma unroll
  for (int v = 0; v < 8; v++) {
    float4 w;
    w.x = acc[v * 4 + 0] * inv; w.y = acc[v * 4 + 1] * inv;
    w.z = acc[v * 4 + 2] * inv; w.w = acc[v * 4 + 3] * inv;
    *reinterpret_cast<float4*>(&out[(size_t)row * 256 + c0 + v * 4]) = w;
  }
}

extern "C" void kernel_launch(void* const* d_in, const int* in_sizes, int n_in,
                              void* d_out, int out_size, void* d_ws, size_t ws_size,
                              hipStream_t stream)
{
  const float* x  = (const float*)d_in[0];
  const float* Wq = (const float*)d_in[1];
  const float* Wk = (const float*)d_in[2];
  const float* Wv = (const float*)d_in[3];

  char* ws = (char*)d_ws;
  unsigned short* qb  = (unsigned short*)ws;                              // 4 MB
  unsigned short* kb  = (unsigned short*)(ws + (size_t)4  * 1024 * 1024); // 4 MB
  unsigned short* vtb = (unsigned short*)(ws + (size_t)8  * 1024 * 1024); // 4 MB
  float*          ml  = (float*)         (ws + (size_t)12 * 1024 * 1024); // 512 KB
  unsigned short* pOb = (unsigned short*)(ws + (size_t)13 * 1024 * 1024); // 32 MB

  proj_kernel<<<dim3(64, 2, 3), 256, 0, stream>>>(x, Wq, Wk, Wv, qb, kb, vtb);
  attn_kernel<<<dim3(NTASKS), 512, 0, stream>>>(qb, kb, vtb, pOb, ml);
  merge_kernel<<<dim3(SEQ / 32), 256, 0, stream>>>(pOb, ml, (float*)d_out);
}